// Round 5
// baseline (219.833 us; speedup 1.0000x reference)
//
#include <hip/hip_runtime.h>
#include <math.h>

// RCC criss-cross attention, MFMA-bf16 pipeline. B=8, C=192, CQK=64, H=W=128.
//
//  kwcast : Wq|Wk|Wv fp32 -> Wb bf16 pre-swizzled per-phase LDS image; bias
//  kxt    : x fp32 -> xT bf16, pre-swizzled per-(b,h,phase) LDS image
//  kprojM : pipelined gll GEMM -> Qc,Kc [b][w][h][c], Vn [b][c][h][w]
//  ktrv   : V transpose -> Vc [b][c][w][h]
//  kC     : per (b,w): e_h MFMA (diag) -> Mh,Sh; P -> PV MFMA -> O2 [b][h][w][c]
//  kR     : per (b,h): e_w MFMA -> local stats; swapped PV in 2 V-halves;
//           merge stats; out = gamma*(O1*scw + O2*sch) + x
//
// kR LDS = 58 KB -> 2 blocks/CU (was 132 KB -> 1). O2 read direct from global.
// xT aliases O2's ws region (xT dead before kC writes O2).

#define B_   8
#define C_   192
#define CQK_ 64
#define H_   128
#define W_   128
#define HW_  (H_*W_)

typedef unsigned short u16;
typedef __attribute__((ext_vector_type(8))) short    s16x8;
typedef __attribute__((ext_vector_type(4))) float    f32x4;
typedef __attribute__((ext_vector_type(2))) unsigned u32x2;
#define MFMA_BF16 __builtin_amdgcn_mfma_f32_16x16x32_bf16

__device__ __forceinline__ u16 f2b(float f) {
    unsigned u = __float_as_uint(f);
    return (u16)((u + 0x7fffu + ((u >> 16) & 1u)) >> 16);   // RNE
}
__device__ __forceinline__ float b2f(u16 v) {
    return __uint_as_float(((unsigned)v) << 16);
}
// raw global->LDS 16B/lane: LDS dest = m0 + lane*16 (wave-uniform m0)
__device__ __forceinline__ void gll16(const u16* gsrc, unsigned lds_byte) {
    asm volatile("s_mov_b32 m0, %1\n\t"
                 "global_load_lds_dwordx4 %0, off"
                 :: "v"(gsrc), "s"(lds_byte) : "memory");
}

// ------------------------------------------------ W -> bf16 pre-swizzled + bias
__global__ __launch_bounds__(256) void kwcast(
    const float* __restrict__ Wq, const float* __restrict__ bq,
    const float* __restrict__ Wk, const float* __restrict__ bk,
    const float* __restrict__ Wv, const float* __restrict__ bv,
    u16* __restrict__ Wb, float* __restrict__ Bb)
{
    const int o = blockIdx.x;                // 320 rows
    const float *row, *bias; int oo;
    if (o < 64)        { row = Wq; bias = bq; oo = o;       }
    else if (o < 128)  { row = Wk; bias = bk; oo = o - 64;  }
    else               { row = Wv; bias = bv; oo = o - 128; }
    const int t = threadIdx.x;
    if (t < C_) {
        const int p = t >> 6, cc = t & 63;
        Wb[p*20480 + o*64 + (((cc >> 3) ^ (o & 7)) << 3) + (cc & 7)]
            = f2b(row[oo*C_ + t]);
    }
    if (t == C_) Bb[o] = bias[oo];
}

// ------------------- x fp32 -> xT bf16 LDS-image [b][h][p][w][chunk^(w&7)][8]
__global__ __launch_bounds__(256) void kxt(
    const float* __restrict__ x, u16* __restrict__ xT)
{
    __shared__ u16 T[24576];                 // 48 KB: [c][16 swz chunks][8]
    const int h = blockIdx.x, b = blockIdx.y;
    const float* xb = x + (size_t)b*C_*HW_ + h*W_;
    const int t = threadIdx.x;
    #pragma unroll
    for (int i = 0; i < 24; ++i) {           // stage + cast
        const int ridx = i*256 + t;
        const int c = ridx >> 5, wq = (ridx & 31) << 2;
        const f32x4 v = *(const f32x4*)(const void*)(xb + (size_t)c*HW_ + wq);
        u32x2 pk;
        pk.x = (unsigned)f2b(v[0]) | ((unsigned)f2b(v[1]) << 16);
        pk.y = (unsigned)f2b(v[2]) | ((unsigned)f2b(v[3]) << 16);
        *(u32x2*)(void*)&T[c*128 + (((wq >> 3) ^ ((c >> 3) & 15)) << 3) + (wq & 7)] = pk;
    }
    __syncthreads();
    u16* dst = xT + (size_t)(b*H_ + h)*24576;
    #pragma unroll
    for (int i = 0; i < 12; ++i) {           // emit transposed image
        const int oidx = i*256 + t;
        const int p = oidx >> 10, w = (oidx >> 3) & 127, cp = oidx & 7;
        s16x8 pk;
        #pragma unroll
        for (int e = 0; e < 8; ++e) {
            const int c = p*64 + ((cp ^ (w & 7)) << 3) + e;
            pk[e] = (short)T[c*128 + ((((w >> 3)) ^ ((c >> 3) & 15)) << 3) + (w & 7)];
        }
        *(s16x8*)(void*)(dst + p*8192 + w*64 + cp*8) = pk;
    }
}

// ---------------------------------------------------- MFMA projection GEMM
__global__ __launch_bounds__(256, 2) void kprojM(
    const u16* __restrict__ xT,
    const u16* __restrict__ Wb, const float* __restrict__ Bb,
    u16* __restrict__ Qc, u16* __restrict__ Kc, u16* __restrict__ Vn)
{
    __shared__ u16 lds[36864];               // 72 KB
    u16* ldsW = lds + 16384;
    u16* ldsV = lds + 8192;
    const int h = blockIdx.x, b = blockIdx.y;
    const int t = threadIdx.x, lane = t & 63, wid = t >> 6;
    const int l15 = lane & 15, q = lane >> 4;

    f32x4 acc[8][5];
    #pragma unroll
    for (int ct = 0; ct < 5; ++ct) {
        const float bv = Bb[(ct*4 + wid)*16 + l15];
        #pragma unroll
        for (int r = 0; r < 8; ++r) acc[r][ct] = (f32x4){bv, bv, bv, bv};
    }

    const u16* xTb = xT + (size_t)(b*H_ + h)*24576;
    const unsigned wofs = __builtin_amdgcn_readfirstlane(32768u + (unsigned)wid*1024u);
    const unsigned aofs = __builtin_amdgcn_readfirstlane((unsigned)wid*1024u);

#define STAGE_W(p) do {                                                   \
    const u16* g = Wb + (p)*20480 + wid*512 + lane*8;                     \
    _Pragma("unroll")                                                     \
    for (int i = 0; i < 10; ++i) gll16(g + i*2048, wofs + i*4096); } while(0)
#define STAGE_A(p, ab) do {                                               \
    const u16* g = xTb + (p)*8192 + wid*512 + lane*8;                     \
    _Pragma("unroll")                                                     \
    for (int i = 0; i < 4; ++i)                                           \
        gll16(g + i*2048, aofs + (ab)*16384u + i*4096); } while(0)
#define MFMA_PHASE(ab) do {                                               \
    const u16* bA = lds + (ab)*8192;                                      \
    __builtin_amdgcn_s_setprio(1);                                        \
    _Pragma("unroll")                                                     \
    for (int ks = 0; ks < 2; ++ks) {                                      \
        s16x8 bf[5];                                                      \
        _Pragma("unroll")                                                 \
        for (int ct = 0; ct < 5; ++ct) {                                  \
            const int o = (ct*4 + wid)*16 + l15;                          \
            bf[ct] = *(const s16x8*)(const void*)                         \
                     &ldsW[o*64 + (((ks*4 + q) ^ (o & 7)) << 3)];         \
        }                                                                 \
        _Pragma("unroll")                                                 \
        for (int r = 0; r < 8; ++r) {                                     \
            const int w = r*16 + l15;                                     \
            const s16x8 af = *(const s16x8*)(const void*)                 \
                     &bA[w*64 + (((ks*4 + q) ^ (w & 7)) << 3)];           \
            _Pragma("unroll")                                             \
            for (int ct = 0; ct < 5; ++ct)                                \
                acc[r][ct] = MFMA_BF16(af, bf[ct], acc[r][ct], 0, 0, 0);  \
        }                                                                 \
    }                                                                     \
    __builtin_amdgcn_s_setprio(0); } while(0)

    STAGE_W(0); STAGE_A(0, 0); STAGE_A(1, 1);            // 18 in flight
    asm volatile("s_waitcnt vmcnt(4)" ::: "memory");     // W0+A0 landed
    __builtin_amdgcn_s_barrier();
    MFMA_PHASE(0);
    asm volatile("s_waitcnt lgkmcnt(0)" ::: "memory");
    __builtin_amdgcn_s_barrier();
    STAGE_W(1); STAGE_A(2, 0);                           // A1 + 14 in flight
    asm volatile("s_waitcnt vmcnt(4)" ::: "memory");     // A1+W1 landed
    __builtin_amdgcn_s_barrier();
    MFMA_PHASE(1);
    asm volatile("s_waitcnt lgkmcnt(0)" ::: "memory");
    __builtin_amdgcn_s_barrier();
    STAGE_W(2);
    asm volatile("s_waitcnt vmcnt(0)" ::: "memory");
    __builtin_amdgcn_s_barrier();
    MFMA_PHASE(0);
    asm volatile("s_waitcnt lgkmcnt(0)" ::: "memory");
    __builtin_amdgcn_s_barrier();

    // ---- epilogue: Q/K direct (32B segments), V via LDS transpose
    {
        const int oc = wid*16 + l15;
        #pragma unroll
        for (int r = 0; r < 8; ++r)
            #pragma unroll
            for (int rg = 0; rg < 4; ++rg) {
                const int w = r*16 + q*4 + rg;
                const size_t base = ((size_t)(b*W_ + w)*H_ + h)*CQK_ + oc;
                Qc[base] = f2b(acc[r][0][rg]);
                Kc[base] = f2b(acc[r][1][rg]);
            }
    }
    #pragma unroll
    for (int ct = 2; ct < 5; ++ct) {
        const int c = (ct - 2)*64 + wid*16 + l15;
        #pragma unroll
        for (int r = 0; r < 8; ++r) {
            const int w0 = r*16 + q*4;
            u32x2 pk;
            pk.x = (unsigned)f2b(acc[r][ct][0]) | ((unsigned)f2b(acc[r][ct][1]) << 16);
            pk.y = (unsigned)f2b(acc[r][ct][2]) | ((unsigned)f2b(acc[r][ct][3]) << 16);
            *(u32x2*)(void*)&ldsV[c*128 + (((w0 >> 3) ^ (c & 7)) << 3) + (w0 & 7)] = pk;
        }
    }
    asm volatile("s_waitcnt lgkmcnt(0)" ::: "memory");
    __builtin_amdgcn_s_barrier();
    #pragma unroll
    for (int i = 0; i < 12; ++i) {
        const int idx = i*256 + t;
        const int c = idx >> 4, j = idx & 15;
        const s16x8 v = *(const s16x8*)(const void*)&ldsV[c*128 + j*8];
        *(s16x8*)(void*)&Vn[(size_t)(b*C_ + c)*HW_ + h*W_ + ((j ^ (c & 7)) << 3)] = v;
    }
#undef STAGE_W
#undef STAGE_A
#undef MFMA_PHASE
}

// ------------------------------------------- V transpose: [c][h][w]->[c][w][h]
__global__ __launch_bounds__(256) void ktrv(
    const u16* __restrict__ Vn, u16* __restrict__ Vc)
{
    __shared__ u16 T[128*128];
    const int c = blockIdx.x, b = blockIdx.y;
    const u16* src = Vn + (size_t)(b*C_ + c)*HW_;
    u16*       dst = Vc + (size_t)(b*C_ + c)*HW_;
    const int t = threadIdx.x;
    for (int idx = t; idx < 128*16; idx += 256) {
        const int hh = idx >> 4, o = idx & 15;
        s16x8 v = *(const s16x8*)(void*)(src + hh*128 + o*8);
        *(s16x8*)(void*)(T + hh*128 + ((o ^ (hh & 7)) << 3)) = v;
    }
    __syncthreads();
    const int w = t & 127, half = t >> 7;
    for (int seg = 0; seg < 8; ++seg) {
        const int h0 = half*64 + seg*8;
        s16x8 pk;
        #pragma unroll
        for (int k = 0; k < 8; ++k) {
            const int hh = h0 + k;
            const int chunk = (w >> 3) ^ (hh & 7);
            pk[k] = (short)T[hh*128 + (chunk << 3) + (w & 7)];
        }
        *(s16x8*)(void*)(dst + w*128 + h0) = pk;
    }
}

// ------------------- column attention (per b,w): O2 raw + Mh,Sh  [512 thr]
__global__ __launch_bounds__(512) void kC(
    const u16* __restrict__ Qc, const u16* __restrict__ Kc,
    const u16* __restrict__ Vc,
    u16* __restrict__ O2, float* __restrict__ Mh, float* __restrict__ Sh)
{
    extern __shared__ char smem[];
    char* ldsQ = smem;
    char* ldsK = smem + 16384;
    char* ldsP = smem;
    char* ldsV = smem + 32768;
    const int w = blockIdx.x, b = blockIdx.y;
    const int t = threadIdx.x, lane = t & 63, wid = t >> 6;
    const int l15 = lane & 15, q = lane >> 4;

    {
        const u16* qs = Qc + (size_t)(b*W_ + w)*H_*CQK_;
        const u16* ks = Kc + (size_t)(b*W_ + w)*H_*CQK_;
        for (int idx = t; idx < 1024; idx += 512) {
            const int r = idx >> 3, o = idx & 7, so = ((o ^ (r & 7)) << 4);
            *(s16x8*)(ldsQ + r*128 + so) = *(const s16x8*)(void*)(qs + idx*8);
            *(s16x8*)(ldsK + r*128 + so) = *(const s16x8*)(void*)(ks + idx*8);
        }
        for (int idx = t; idx < 3072; idx += 512) {
            const int c = idx >> 4, o = idx & 15;
            s16x8 v = *(const s16x8*)(void*)
                      (Vc + ((size_t)(b*C_ + c)*W_ + w)*H_ + o*8);
            *(s16x8*)(ldsV + c*256 + ((o ^ (c & 7)) << 4)) = v;
        }
    }
    __syncthreads();

    f32x4 accS[8];
    #pragma unroll
    for (int i = 0; i < 8; ++i) accS[i] = (f32x4){0.f,0.f,0.f,0.f};
    const int arow = (wid << 4) + l15;
    #pragma unroll
    for (int ks = 0; ks < 2; ++ks) {
        const int ch = ks*4 + q;
        s16x8 af = *(const s16x8*)(ldsQ + arow*128 + ((ch ^ (arow & 7)) << 4));
        #pragma unroll
        for (int gt = 0; gt < 8; ++gt) {
            const int br = (gt << 4) + l15;
            s16x8 bf = *(const s16x8*)(ldsK + br*128 + ((ch ^ (br & 7)) << 4));
            accS[gt] = MFMA_BF16(af, bf, accS[gt], 0, 0, 0);
        }
    }
    __syncthreads();

    #pragma unroll
    for (int r = 0; r < 4; ++r) {
        const int hh = (wid << 4) + (q << 2) + r;
        #pragma unroll
        for (int gt = 0; gt < 8; ++gt)
            if ((gt << 4) + l15 == hh) accS[gt][r] = -3.0e38f;
        float m = -3.0e38f;
        #pragma unroll
        for (int gt = 0; gt < 8; ++gt) m = fmaxf(m, accS[gt][r]);
        m = fmaxf(m, __shfl_xor(m, 1)); m = fmaxf(m, __shfl_xor(m, 2));
        m = fmaxf(m, __shfl_xor(m, 4)); m = fmaxf(m, __shfl_xor(m, 8));
        float s = 0.f;
        #pragma unroll
        for (int gt = 0; gt < 8; ++gt) {
            const float e = __expf(accS[gt][r] - m);
            s += e;
            const int g = (gt << 4) + l15;
            *(u16*)(ldsP + hh*256 + (((g >> 3) ^ (hh & 7)) << 4) + (g & 7)*2)
                = f2b(e);
        }
        s += __shfl_xor(s, 1); s += __shfl_xor(s, 2);
        s += __shfl_xor(s, 4); s += __shfl_xor(s, 8);
        if (l15 == 0) {
            Mh[(b*W_ + w)*H_ + hh] = m;
            Sh[(b*W_ + w)*H_ + hh] = s;
        }
    }
    __syncthreads();

    f32x4 accO[12];
    #pragma unroll
    for (int i = 0; i < 12; ++i) accO[i] = (f32x4){0.f,0.f,0.f,0.f};
    #pragma unroll
    for (int ks = 0; ks < 4; ++ks) {
        const int ch = ks*4 + q;
        const int pr = (wid << 4) + l15;
        s16x8 af = *(const s16x8*)(ldsP + pr*256 + ((ch ^ (pr & 7)) << 4));
        #pragma unroll
        for (int ct = 0; ct < 12; ++ct) {
            const int vr = (ct << 4) + l15;
            s16x8 bf = *(const s16x8*)(ldsV + vr*256 + ((ch ^ (vr & 7)) << 4));
            accO[ct] = MFMA_BF16(af, bf, accO[ct], 0, 0, 0);
        }
    }
    // O2 layout [b][h][w][c]  (kR reads it contiguously per (h,w))
    #pragma unroll
    for (int ct = 0; ct < 12; ++ct) {
        const int c = (ct << 4) + l15;
        #pragma unroll
        for (int r = 0; r < 4; ++r) {
            const int hh = (wid << 4) + (q << 2) + r;
            O2[((size_t)(b*H_ + hh)*W_ + w)*C_ + c] = f2b(accO[ct][r]);
        }
    }
}

// -------- row attention + fused final (per b,h)  [512 thr, 58KB LDS, 2/CU]
__global__ __launch_bounds__(512, 4) void kR(
    const u16* __restrict__ Qc, const u16* __restrict__ Kc,
    const u16* __restrict__ Vn, const u16* __restrict__ O2,
    const float* __restrict__ Mh, const float* __restrict__ Sh,
    const float* __restrict__ x, const float* __restrict__ gamma,
    float* __restrict__ out)
{
    extern __shared__ char smem[];
    char*  ldsQ = smem;                      // 16K
    char*  ldsK = smem + 16384;              // 16K
    char*  ldsP = smem;                      // 32K reuse after QK
    char*  ldsV = smem + 32768;              // 24K: one 96-channel half
    float* sMh = (float*)(smem + 57344);
    float* sSh = sMh + 128;
    float* sMw = sSh + 128;
    float* sSw = sMw + 128;
    const int h = blockIdx.x, b = blockIdx.y;
    const int t = threadIdx.x, lane = t & 63, wid = t >> 6;
    const int l15 = lane & 15, q = lane >> 4;
    const float gam = gamma[0];

    // ---- T14: issue V half2 (c 96..191) global loads NOW, ds_write later
    s16x8 vh2[3];
    #pragma unroll
    for (int i = 0; i < 3; ++i) {
        const int idx = i*512 + t;           // 0..1535
        const int c = 96 + (idx >> 4), o = idx & 15;
        vh2[i] = *(const s16x8*)(void*)(Vn + (size_t)(b*C_ + c)*HW_ + h*W_ + o*8);
    }
    // ---- stage Q,K (swizzled)
    for (int idx = t; idx < 1024; idx += 512) {
        const int r = idx >> 3, o = idx & 7, so = ((o ^ (r & 7)) << 4);
        const size_t g = ((size_t)(b*W_ + r)*H_ + h)*CQK_ + o*8;
        *(s16x8*)(ldsQ + r*128 + so) = *(const s16x8*)(void*)(Qc + g);
        *(s16x8*)(ldsK + r*128 + so) = *(const s16x8*)(void*)(Kc + g);
    }
    // ---- stage V half1 (c 0..95)
    for (int idx = t; idx < 1536; idx += 512) {
        const int c = idx >> 4, o = idx & 15;
        s16x8 v = *(const s16x8*)(void*)
                  (Vn + (size_t)(b*C_ + c)*HW_ + h*W_ + o*8);
        *(s16x8*)(ldsV + c*256 + ((o ^ (c & 7)) << 4)) = v;
    }
    if (t < 128) {
        sMh[t] = Mh[(b*W_ + t)*H_ + h];
        sSh[t] = Sh[(b*W_ + t)*H_ + h];
    }
    __syncthreads();

    // ---- scores: e_w[w][v]
    f32x4 accS[8];
    #pragma unroll
    for (int i = 0; i < 8; ++i) accS[i] = (f32x4){0.f,0.f,0.f,0.f};
    const int arow = (wid << 4) + l15;
    #pragma unroll
    for (int ks = 0; ks < 2; ++ks) {
        const int ch = ks*4 + q;
        s16x8 af = *(const s16x8*)(ldsQ + arow*128 + ((ch ^ (arow & 7)) << 4));
        #pragma unroll
        for (int vt = 0; vt < 8; ++vt) {
            const int br = (vt << 4) + l15;
            s16x8 bf = *(const s16x8*)(ldsK + br*128 + ((ch ^ (br & 7)) << 4));
            accS[vt] = MFMA_BF16(af, bf, accS[vt], 0, 0, 0);
        }
    }
    __syncthreads();

    // ---- row stats + P = exp(e - Mw)
    #pragma unroll
    for (int r = 0; r < 4; ++r) {
        const int ww = (wid << 4) + (q << 2) + r;
        float m = -3.0e38f;
        #pragma unroll
        for (int vt = 0; vt < 8; ++vt) m = fmaxf(m, accS[vt][r]);
        m = fmaxf(m, __shfl_xor(m, 1)); m = fmaxf(m, __shfl_xor(m, 2));
        m = fmaxf(m, __shfl_xor(m, 4)); m = fmaxf(m, __shfl_xor(m, 8));
        float s = 0.f;
        #pragma unroll
        for (int vt = 0; vt < 8; ++vt) {
            const float e = __expf(accS[vt][r] - m);
            s += e;
            const int v = (vt << 4) + l15;
            *(u16*)(ldsP + ww*256 + (((v >> 3) ^ (ww & 7)) << 4) + (v & 7)*2)
                = f2b(e);
        }
        s += __shfl_xor(s, 1); s += __shfl_xor(s, 2);
        s += __shfl_xor(s, 4); s += __shfl_xor(s, 8);
        if (l15 == 0) { sMw[ww] = m; sSw[ww] = s; }
    }
    __syncthreads();

    // ---- PV half1: D[c][w], c 0..95  (A=V, B=P)
    const int prow = (wid << 4) + l15;       // B col = w
    f32x4 accO[6];
    #pragma unroll
    for (int i = 0; i < 6; ++i) accO[i] = (f32x4){0.f,0.f,0.f,0.f};
    #pragma unroll
    for (int ks = 0; ks < 4; ++ks) {
        const int ch = ks*4 + q;
        s16x8 bfp = *(const s16x8*)(ldsP + prow*256 + ((ch ^ (prow & 7)) << 4));
        #pragma unroll
        for (int ct = 0; ct < 6; ++ct) {
            const int vr = (ct << 4) + l15;
            s16x8 afv = *(const s16x8*)(ldsV + vr*256 + ((ch ^ (vr & 7)) << 4));
            accO[ct] = MFMA_BF16(afv, bfp, accO[ct], 0, 0, 0);
        }
    }
    __syncthreads();                         // PV1 done reading ldsV

    // ---- ds_write V half2 (latency covered by epilogue half1's VMEM)
    #pragma unroll
    for (int i = 0; i < 3; ++i) {
        const int idx = i*512 + t;
        const int lc = idx >> 4, o = idx & 15;   // lc = c-96
        *(s16x8*)(ldsV + lc*256 + ((o ^ ((lc + 96) & 7)) << 4)) = vh2[i];
    }

    // ---- merged softmax scales (per-lane ww)
    const int ww = (wid << 4) + l15;
    const float mh = sMh[ww], shv = sSh[ww];
    const float mw = sMw[ww], swv = sSw[ww];
    const float M  = fmaxf(mh, mw);
    const float S  = shv*__expf(mh - M) + swv*__expf(mw - M);
    const float scw = __expf(mw - M) / S;
    const float sch = __expf(mh - M) / S;
    const u16* o2p = O2 + ((size_t)(b*H_ + h)*W_ + ww)*C_;
    const size_t gb = (size_t)b*C_*HW_ + h*W_ + ww;

    // ---- epilogue half1: c 0..95
    #pragma unroll
    for (int ct = 0; ct < 6; ++ct) {
        #pragma unroll
        for (int r = 0; r < 4; ++r) {
            const int c = ct*16 + q*4 + r;
            const float o2 = b2f(o2p[c]);
            const size_t ga = gb + (size_t)c*HW_;
            out[ga] = gam*(accO[ct][r]*scw + o2*sch) + x[ga];
        }
    }
    __syncthreads();                         // V half2 visible

    // ---- PV half2: c 96..191
    f32x4 accO2[6];
    #pragma unroll
    for (int i = 0; i < 6; ++i) accO2[i] = (f32x4){0.f,0.f,0.f,0.f};
    #pragma unroll
    for (int ks = 0; ks < 4; ++ks) {
        const int ch = ks*4 + q;
        s16x8 bfp = *(const s16x8*)(ldsP + prow*256 + ((ch ^ (prow & 7)) << 4));
        #pragma unroll
        for (int ct = 0; ct < 6; ++ct) {
            const int lr = (ct << 4) + l15;      // local V row = c-96
            s16x8 afv = *(const s16x8*)(ldsV + lr*256 + ((ch ^ ((lr + 96) & 7)) << 4));
            accO2[ct] = MFMA_BF16(afv, bfp, accO2[ct], 0, 0, 0);
        }
    }
    // ---- epilogue half2: c 96..191
    #pragma unroll
    for (int ct = 0; ct < 6; ++ct) {
        #pragma unroll
        for (int r = 0; r < 4; ++r) {
            const int c = 96 + ct*16 + q*4 + r;
            const float o2 = b2f(o2p[c]);
            const size_t ga = gb + (size_t)c*HW_;
            out[ga] = gam*(accO2[ct][r]*scw + o2*sch) + x[ga];
        }
    }
}

extern "C" void kernel_launch(void* const* d_in, const int* in_sizes, int n_in,
                              void* d_out, int out_size, void* d_ws, size_t ws_size,
                              hipStream_t stream)
{
    const float* x  = (const float*)d_in[0];
    const float* Wq = (const float*)d_in[1];
    const float* bq = (const float*)d_in[2];
    const float* Wk = (const float*)d_in[3];
    const float* bk = (const float*)d_in[4];
    const float* Wv = (const float*)d_in[5];
    const float* bv = (const float*)d_in[6];
    const float* gm = (const float*)d_in[7];
    float* out = (float*)d_out;

    u16* Qc = (u16*)d_ws;
    u16* Kc = Qc + 8388608;
    u16* Vn = Kc + 8388608;
    u16* Vc = Vn + 25165824;
    u16* O2 = Vc + 25165824;                 // 25165824 u16
    u16* xT = O2;                            // alias: xT dead before kC writes O2
    float* Mh = (float*)(O2 + 25165824);
    float* Sh = Mh + 131072;
    u16*  Wb = (u16*)(Sh + 131072);          // 61440 u16
    float* Bb = (float*)(Wb + 61440);        // 320 f32

    hipLaunchKernelGGL(kwcast, dim3(320), dim3(256), 0, stream,
                       Wq, bq, Wk, bk, Wv, bv, Wb, Bb);
    hipLaunchKernelGGL(kxt, dim3(H_, B_), dim3(256), 0, stream, x, xT);
    hipLaunchKernelGGL(kprojM, dim3(H_, B_), dim3(256), 0, stream,
                       xT, Wb, Bb, Qc, Kc, Vn);
    hipLaunchKernelGGL(ktrv, dim3(C_, B_), dim3(256), 0, stream, Vn, Vc);
    hipLaunchKernelGGL(kC, dim3(W_, B_), dim3(512), 81920, stream,
                       Qc, Kc, Vc, O2, Mh, Sh);
    hipLaunchKernelGGL(kR, dim3(H_, B_), dim3(512), 59392, stream,
                       Qc, Kc, Vn, O2, Mh, Sh, x, gm, out);
}

// Round 6
// 186.134 us; speedup vs baseline: 1.1810x; 1.1810x over previous
//
#include <hip/hip_runtime.h>
#include <math.h>

// RCC criss-cross attention, MFMA-bf16 pipeline. B=8, C=192, CQK=64, H=W=128.
//
//  kwcast : Wq|Wk|Wv fp32 -> Wb bf16 pre-swizzled per-phase LDS image; bias
//  kxt    : x fp32 -> xT bf16, pre-swizzled per-(b,h,phase) LDS image
//  kprojM : pipelined gll GEMM -> Qc,Kc [b][w][h][c], Vn [b][c][h][w]
//  ktrv   : V transpose -> Vc [b][c][w][h]
//  kC     : per (b,w): e_h MFMA (diag) -> Mh,Sh; P -> PV MFMA -> O2 [b][h][w][c]
//  kR     : per (b,h): e_w MFMA -> local stats; non-swapped PV (thread owns
//           4 consecutive w) -> f32x4 x/out epilogue; O2/x reg-prefetched.
//
// kR LDS = 59 KB -> 2 blocks/CU. xT aliases O2's ws region.

#define B_   8
#define C_   192
#define CQK_ 64
#define H_   128
#define W_   128
#define HW_  (H_*W_)

typedef unsigned short u16;
typedef __attribute__((ext_vector_type(8))) short    s16x8;
typedef __attribute__((ext_vector_type(4))) float    f32x4;
typedef __attribute__((ext_vector_type(2))) unsigned u32x2;
#define MFMA_BF16 __builtin_amdgcn_mfma_f32_16x16x32_bf16

__device__ __forceinline__ u16 f2b(float f) {
    unsigned u = __float_as_uint(f);
    return (u16)((u + 0x7fffu + ((u >> 16) & 1u)) >> 16);   // RNE
}
__device__ __forceinline__ float b2f(u16 v) {
    return __uint_as_float(((unsigned)v) << 16);
}
// raw global->LDS 16B/lane: LDS dest = m0 + lane*16 (wave-uniform m0)
__device__ __forceinline__ void gll16(const u16* gsrc, unsigned lds_byte) {
    asm volatile("s_mov_b32 m0, %1\n\t"
                 "global_load_lds_dwordx4 %0, off"
                 :: "v"(gsrc), "s"(lds_byte) : "memory");
}

// ------------------------------------------------ W -> bf16 pre-swizzled + bias
__global__ __launch_bounds__(256) void kwcast(
    const float* __restrict__ Wq, const float* __restrict__ bq,
    const float* __restrict__ Wk, const float* __restrict__ bk,
    const float* __restrict__ Wv, const float* __restrict__ bv,
    u16* __restrict__ Wb, float* __restrict__ Bb)
{
    const int o = blockIdx.x;                // 320 rows
    const float *row, *bias; int oo;
    if (o < 64)        { row = Wq; bias = bq; oo = o;       }
    else if (o < 128)  { row = Wk; bias = bk; oo = o - 64;  }
    else               { row = Wv; bias = bv; oo = o - 128; }
    const int t = threadIdx.x;
    if (t < C_) {
        const int p = t >> 6, cc = t & 63;
        Wb[p*20480 + o*64 + (((cc >> 3) ^ (o & 7)) << 3) + (cc & 7)]
            = f2b(row[oo*C_ + t]);
    }
    if (t == C_) Bb[o] = bias[oo];
}

// ------------------- x fp32 -> xT bf16 LDS-image [b][h][p][w][chunk^(w&7)][8]
__global__ __launch_bounds__(256) void kxt(
    const float* __restrict__ x, u16* __restrict__ xT)
{
    __shared__ u16 T[24576];                 // 48 KB: [c][16 swz chunks][8]
    const int h = blockIdx.x, b = blockIdx.y;
    const float* xb = x + (size_t)b*C_*HW_ + h*W_;
    const int t = threadIdx.x;
    #pragma unroll
    for (int i = 0; i < 24; ++i) {           // stage + cast
        const int ridx = i*256 + t;
        const int c = ridx >> 5, wq = (ridx & 31) << 2;
        const f32x4 v = *(const f32x4*)(const void*)(xb + (size_t)c*HW_ + wq);
        u32x2 pk;
        pk.x = (unsigned)f2b(v[0]) | ((unsigned)f2b(v[1]) << 16);
        pk.y = (unsigned)f2b(v[2]) | ((unsigned)f2b(v[3]) << 16);
        *(u32x2*)(void*)&T[c*128 + (((wq >> 3) ^ ((c >> 3) & 15)) << 3) + (wq & 7)] = pk;
    }
    __syncthreads();
    u16* dst = xT + (size_t)(b*H_ + h)*24576;
    #pragma unroll
    for (int i = 0; i < 12; ++i) {           // emit transposed image
        const int oidx = i*256 + t;
        const int p = oidx >> 10, w = (oidx >> 3) & 127, cp = oidx & 7;
        s16x8 pk;
        #pragma unroll
        for (int e = 0; e < 8; ++e) {
            const int c = p*64 + ((cp ^ (w & 7)) << 3) + e;
            pk[e] = (short)T[c*128 + ((((w >> 3)) ^ ((c >> 3) & 15)) << 3) + (w & 7)];
        }
        *(s16x8*)(void*)(dst + p*8192 + w*64 + cp*8) = pk;
    }
}

// ---------------------------------------------------- MFMA projection GEMM
__global__ __launch_bounds__(256, 2) void kprojM(
    const u16* __restrict__ xT,
    const u16* __restrict__ Wb, const float* __restrict__ Bb,
    u16* __restrict__ Qc, u16* __restrict__ Kc, u16* __restrict__ Vn)
{
    __shared__ u16 lds[36864];               // 72 KB
    u16* ldsW = lds + 16384;
    u16* ldsV = lds + 8192;
    const int h = blockIdx.x, b = blockIdx.y;
    const int t = threadIdx.x, lane = t & 63, wid = t >> 6;
    const int l15 = lane & 15, q = lane >> 4;

    f32x4 acc[8][5];
    #pragma unroll
    for (int ct = 0; ct < 5; ++ct) {
        const float bv = Bb[(ct*4 + wid)*16 + l15];
        #pragma unroll
        for (int r = 0; r < 8; ++r) acc[r][ct] = (f32x4){bv, bv, bv, bv};
    }

    const u16* xTb = xT + (size_t)(b*H_ + h)*24576;
    const unsigned wofs = __builtin_amdgcn_readfirstlane(32768u + (unsigned)wid*1024u);
    const unsigned aofs = __builtin_amdgcn_readfirstlane((unsigned)wid*1024u);

#define STAGE_W(p) do {                                                   \
    const u16* g = Wb + (p)*20480 + wid*512 + lane*8;                     \
    _Pragma("unroll")                                                     \
    for (int i = 0; i < 10; ++i) gll16(g + i*2048, wofs + i*4096); } while(0)
#define STAGE_A(p, ab) do {                                               \
    const u16* g = xTb + (p)*8192 + wid*512 + lane*8;                     \
    _Pragma("unroll")                                                     \
    for (int i = 0; i < 4; ++i)                                           \
        gll16(g + i*2048, aofs + (ab)*16384u + i*4096); } while(0)
#define MFMA_PHASE(ab) do {                                               \
    const u16* bA = lds + (ab)*8192;                                      \
    __builtin_amdgcn_s_setprio(1);                                        \
    _Pragma("unroll")                                                     \
    for (int ks = 0; ks < 2; ++ks) {                                      \
        s16x8 bf[5];                                                      \
        _Pragma("unroll")                                                 \
        for (int ct = 0; ct < 5; ++ct) {                                  \
            const int o = (ct*4 + wid)*16 + l15;                          \
            bf[ct] = *(const s16x8*)(const void*)                         \
                     &ldsW[o*64 + (((ks*4 + q) ^ (o & 7)) << 3)];         \
        }                                                                 \
        _Pragma("unroll")                                                 \
        for (int r = 0; r < 8; ++r) {                                     \
            const int w = r*16 + l15;                                     \
            const s16x8 af = *(const s16x8*)(const void*)                 \
                     &bA[w*64 + (((ks*4 + q) ^ (w & 7)) << 3)];           \
            _Pragma("unroll")                                             \
            for (int ct = 0; ct < 5; ++ct)                                \
                acc[r][ct] = MFMA_BF16(af, bf[ct], acc[r][ct], 0, 0, 0);  \
        }                                                                 \
    }                                                                     \
    __builtin_amdgcn_s_setprio(0); } while(0)

    STAGE_W(0); STAGE_A(0, 0); STAGE_A(1, 1);            // 18 in flight
    asm volatile("s_waitcnt vmcnt(4)" ::: "memory");     // W0+A0 landed
    __builtin_amdgcn_s_barrier();
    MFMA_PHASE(0);
    asm volatile("s_waitcnt lgkmcnt(0)" ::: "memory");
    __builtin_amdgcn_s_barrier();
    STAGE_W(1); STAGE_A(2, 0);                           // A1 + 14 in flight
    asm volatile("s_waitcnt vmcnt(4)" ::: "memory");     // A1+W1 landed
    __builtin_amdgcn_s_barrier();
    MFMA_PHASE(1);
    asm volatile("s_waitcnt lgkmcnt(0)" ::: "memory");
    __builtin_amdgcn_s_barrier();
    STAGE_W(2);
    asm volatile("s_waitcnt vmcnt(0)" ::: "memory");
    __builtin_amdgcn_s_barrier();
    MFMA_PHASE(0);
    asm volatile("s_waitcnt lgkmcnt(0)" ::: "memory");
    __builtin_amdgcn_s_barrier();

    // ---- epilogue: Q/K direct (32B segments), V via LDS transpose
    {
        const int oc = wid*16 + l15;
        #pragma unroll
        for (int r = 0; r < 8; ++r)
            #pragma unroll
            for (int rg = 0; rg < 4; ++rg) {
                const int w = r*16 + q*4 + rg;
                const size_t base = ((size_t)(b*W_ + w)*H_ + h)*CQK_ + oc;
                Qc[base] = f2b(acc[r][0][rg]);
                Kc[base] = f2b(acc[r][1][rg]);
            }
    }
    #pragma unroll
    for (int ct = 2; ct < 5; ++ct) {
        const int c = (ct - 2)*64 + wid*16 + l15;
        #pragma unroll
        for (int r = 0; r < 8; ++r) {
            const int w0 = r*16 + q*4;
            u32x2 pk;
            pk.x = (unsigned)f2b(acc[r][ct][0]) | ((unsigned)f2b(acc[r][ct][1]) << 16);
            pk.y = (unsigned)f2b(acc[r][ct][2]) | ((unsigned)f2b(acc[r][ct][3]) << 16);
            *(u32x2*)(void*)&ldsV[c*128 + (((w0 >> 3) ^ (c & 7)) << 3) + (w0 & 7)] = pk;
        }
    }
    asm volatile("s_waitcnt lgkmcnt(0)" ::: "memory");
    __builtin_amdgcn_s_barrier();
    #pragma unroll
    for (int i = 0; i < 12; ++i) {
        const int idx = i*256 + t;
        const int c = idx >> 4, j = idx & 15;
        const s16x8 v = *(const s16x8*)(const void*)&ldsV[c*128 + j*8];
        *(s16x8*)(void*)&Vn[(size_t)(b*C_ + c)*HW_ + h*W_ + ((j ^ (c & 7)) << 3)] = v;
    }
#undef STAGE_W
#undef STAGE_A
#undef MFMA_PHASE
}

// ------------------------------------------- V transpose: [c][h][w]->[c][w][h]
__global__ __launch_bounds__(256) void ktrv(
    const u16* __restrict__ Vn, u16* __restrict__ Vc)
{
    __shared__ u16 T[128*128];
    const int c = blockIdx.x, b = blockIdx.y;
    const u16* src = Vn + (size_t)(b*C_ + c)*HW_;
    u16*       dst = Vc + (size_t)(b*C_ + c)*HW_;
    const int t = threadIdx.x;
    for (int idx = t; idx < 128*16; idx += 256) {
        const int hh = idx >> 4, o = idx & 15;
        s16x8 v = *(const s16x8*)(void*)(src + hh*128 + o*8);
        *(s16x8*)(void*)(T + hh*128 + ((o ^ (hh & 7)) << 3)) = v;
    }
    __syncthreads();
    const int w = t & 127, half = t >> 7;
    for (int seg = 0; seg < 8; ++seg) {
        const int h0 = half*64 + seg*8;
        s16x8 pk;
        #pragma unroll
        for (int k = 0; k < 8; ++k) {
            const int hh = h0 + k;
            const int chunk = (w >> 3) ^ (hh & 7);
            pk[k] = (short)T[hh*128 + (chunk << 3) + (w & 7)];
        }
        *(s16x8*)(void*)(dst + w*128 + h0) = pk;
    }
}

// ------------------- column attention (per b,w): O2 raw + Mh,Sh  [512 thr]
__global__ __launch_bounds__(512) void kC(
    const u16* __restrict__ Qc, const u16* __restrict__ Kc,
    const u16* __restrict__ Vc,
    u16* __restrict__ O2, float* __restrict__ Mh, float* __restrict__ Sh)
{
    extern __shared__ char smem[];
    char* ldsQ = smem;
    char* ldsK = smem + 16384;
    char* ldsP = smem;
    char* ldsV = smem + 32768;
    const int w = blockIdx.x, b = blockIdx.y;
    const int t = threadIdx.x, lane = t & 63, wid = t >> 6;
    const int l15 = lane & 15, q = lane >> 4;

    {
        const u16* qs = Qc + (size_t)(b*W_ + w)*H_*CQK_;
        const u16* ks = Kc + (size_t)(b*W_ + w)*H_*CQK_;
        for (int idx = t; idx < 1024; idx += 512) {
            const int r = idx >> 3, o = idx & 7, so = ((o ^ (r & 7)) << 4);
            *(s16x8*)(ldsQ + r*128 + so) = *(const s16x8*)(void*)(qs + idx*8);
            *(s16x8*)(ldsK + r*128 + so) = *(const s16x8*)(void*)(ks + idx*8);
        }
        for (int idx = t; idx < 3072; idx += 512) {
            const int c = idx >> 4, o = idx & 15;
            s16x8 v = *(const s16x8*)(void*)
                      (Vc + ((size_t)(b*C_ + c)*W_ + w)*H_ + o*8);
            *(s16x8*)(ldsV + c*256 + ((o ^ (c & 7)) << 4)) = v;
        }
    }
    __syncthreads();

    f32x4 accS[8];
    #pragma unroll
    for (int i = 0; i < 8; ++i) accS[i] = (f32x4){0.f,0.f,0.f,0.f};
    const int arow = (wid << 4) + l15;
    #pragma unroll
    for (int ks = 0; ks < 2; ++ks) {
        const int ch = ks*4 + q;
        s16x8 af = *(const s16x8*)(ldsQ + arow*128 + ((ch ^ (arow & 7)) << 4));
        #pragma unroll
        for (int gt = 0; gt < 8; ++gt) {
            const int br = (gt << 4) + l15;
            s16x8 bf = *(const s16x8*)(ldsK + br*128 + ((ch ^ (br & 7)) << 4));
            accS[gt] = MFMA_BF16(af, bf, accS[gt], 0, 0, 0);
        }
    }
    __syncthreads();

    #pragma unroll
    for (int r = 0; r < 4; ++r) {
        const int hh = (wid << 4) + (q << 2) + r;
        #pragma unroll
        for (int gt = 0; gt < 8; ++gt)
            if ((gt << 4) + l15 == hh) accS[gt][r] = -3.0e38f;
        float m = -3.0e38f;
        #pragma unroll
        for (int gt = 0; gt < 8; ++gt) m = fmaxf(m, accS[gt][r]);
        m = fmaxf(m, __shfl_xor(m, 1)); m = fmaxf(m, __shfl_xor(m, 2));
        m = fmaxf(m, __shfl_xor(m, 4)); m = fmaxf(m, __shfl_xor(m, 8));
        float s = 0.f;
        #pragma unroll
        for (int gt = 0; gt < 8; ++gt) {
            const float e = __expf(accS[gt][r] - m);
            s += e;
            const int g = (gt << 4) + l15;
            *(u16*)(ldsP + hh*256 + (((g >> 3) ^ (hh & 7)) << 4) + (g & 7)*2)
                = f2b(e);
        }
        s += __shfl_xor(s, 1); s += __shfl_xor(s, 2);
        s += __shfl_xor(s, 4); s += __shfl_xor(s, 8);
        if (l15 == 0) {
            Mh[(b*W_ + w)*H_ + hh] = m;
            Sh[(b*W_ + w)*H_ + hh] = s;
        }
    }
    __syncthreads();

    f32x4 accO[12];
    #pragma unroll
    for (int i = 0; i < 12; ++i) accO[i] = (f32x4){0.f,0.f,0.f,0.f};
    #pragma unroll
    for (int ks = 0; ks < 4; ++ks) {
        const int ch = ks*4 + q;
        const int pr = (wid << 4) + l15;
        s16x8 af = *(const s16x8*)(ldsP + pr*256 + ((ch ^ (pr & 7)) << 4));
        #pragma unroll
        for (int ct = 0; ct < 12; ++ct) {
            const int vr = (ct << 4) + l15;
            s16x8 bf = *(const s16x8*)(ldsV + vr*256 + ((ch ^ (vr & 7)) << 4));
            accO[ct] = MFMA_BF16(af, bf, accO[ct], 0, 0, 0);
        }
    }
    // O2 layout [b][h][w][c]  (kR reads it per (h,w) row)
    #pragma unroll
    for (int ct = 0; ct < 12; ++ct) {
        const int c = (ct << 4) + l15;
        #pragma unroll
        for (int r = 0; r < 4; ++r) {
            const int hh = (wid << 4) + (q << 2) + r;
            O2[((size_t)(b*H_ + hh)*W_ + w)*C_ + c] = f2b(accO[ct][r]);
        }
    }
}

// -------- row attention + fused final (per b,h)  [512 thr, 59KB LDS, 2/CU]
__global__ __launch_bounds__(512, 4) void kR(
    const u16* __restrict__ Qc, const u16* __restrict__ Kc,
    const u16* __restrict__ Vn, const u16* __restrict__ O2,
    const float* __restrict__ Mh, const float* __restrict__ Sh,
    const float* __restrict__ x, const float* __restrict__ gamma,
    float* __restrict__ out)
{
    extern __shared__ char smem[];
    char*  ldsQ = smem;                      // 16K
    char*  ldsK = smem + 16384;              // 16K
    char*  ldsP = smem;                      // 32K reuse after QK
    char*  ldsV = smem + 32768;              // 24K: one 96-channel half
    float* sMh  = (float*)(smem + 57344);
    float* sSh  = sMh + 128;
    float* sMw  = sSh + 128;
    float* sSw  = sMw + 128;
    float* sScw = sSw + 128;
    float* sSch = sScw + 128;
    const int h = blockIdx.x, b = blockIdx.y;
    const int t = threadIdx.x, lane = t & 63, wid = t >> 6;
    const int l15 = lane & 15, q = lane >> 4;
    const int wbase = wid*16 + q*4;          // this thread's 4 w's (non-swapped D)
    const float gam = gamma[0];

    // ---- prefetch x half1: c = ct*16+l15, w = wbase..+3 (f32x4)
    f32x4 xp1[6];
    #pragma unroll
    for (int ct = 0; ct < 6; ++ct)
        xp1[ct] = *(const f32x4*)(const void*)
                  (x + (size_t)(b*C_ + ct*16 + l15)*HW_ + h*W_ + wbase);
    // ---- V half2 (c 96..191) into regs (T14), ds_write later
    s16x8 vh2[3];
    #pragma unroll
    for (int i = 0; i < 3; ++i) {
        const int idx = i*512 + t;
        const int c = 96 + (idx >> 4), o = idx & 15;
        vh2[i] = *(const s16x8*)(void*)(Vn + (size_t)(b*C_ + c)*HW_ + h*W_ + o*8);
    }
    // ---- stage Q,K (swizzled)
    for (int idx = t; idx < 1024; idx += 512) {
        const int r = idx >> 3, o = idx & 7, so = ((o ^ (r & 7)) << 4);
        const size_t g = ((size_t)(b*W_ + r)*H_ + h)*CQK_ + o*8;
        *(s16x8*)(ldsQ + r*128 + so) = *(const s16x8*)(void*)(Qc + g);
        *(s16x8*)(ldsK + r*128 + so) = *(const s16x8*)(void*)(Kc + g);
    }
    // ---- stage V half1 (c 0..95)
    for (int idx = t; idx < 1536; idx += 512) {
        const int c = idx >> 4, o = idx & 15;
        s16x8 v = *(const s16x8*)(void*)
                  (Vn + (size_t)(b*C_ + c)*HW_ + h*W_ + o*8);
        *(s16x8*)(ldsV + c*256 + ((o ^ (c & 7)) << 4)) = v;
    }
    if (t < 128) {
        sMh[t] = Mh[(b*W_ + t)*H_ + h];
        sSh[t] = Sh[(b*W_ + t)*H_ + h];
    }
    __syncthreads();

    // ---- scores: e_w[w][v]
    f32x4 accS[8];
    #pragma unroll
    for (int i = 0; i < 8; ++i) accS[i] = (f32x4){0.f,0.f,0.f,0.f};
    const int arow = (wid << 4) + l15;
    #pragma unroll
    for (int ks = 0; ks < 2; ++ks) {
        const int ch = ks*4 + q;
        s16x8 af = *(const s16x8*)(ldsQ + arow*128 + ((ch ^ (arow & 7)) << 4));
        #pragma unroll
        for (int vt = 0; vt < 8; ++vt) {
            const int br = (vt << 4) + l15;
            s16x8 bf = *(const s16x8*)(ldsK + br*128 + ((ch ^ (br & 7)) << 4));
            accS[vt] = MFMA_BF16(af, bf, accS[vt], 0, 0, 0);
        }
    }
    __syncthreads();

    // ---- row stats + P = exp(e - Mw)
    #pragma unroll
    for (int r = 0; r < 4; ++r) {
        const int ww = (wid << 4) + (q << 2) + r;
        float m = -3.0e38f;
        #pragma unroll
        for (int vt = 0; vt < 8; ++vt) m = fmaxf(m, accS[vt][r]);
        m = fmaxf(m, __shfl_xor(m, 1)); m = fmaxf(m, __shfl_xor(m, 2));
        m = fmaxf(m, __shfl_xor(m, 4)); m = fmaxf(m, __shfl_xor(m, 8));
        float s = 0.f;
        #pragma unroll
        for (int vt = 0; vt < 8; ++vt) {
            const float e = __expf(accS[vt][r] - m);
            s += e;
            const int v = (vt << 4) + l15;
            *(u16*)(ldsP + ww*256 + (((v >> 3) ^ (ww & 7)) << 4) + (v & 7)*2)
                = f2b(e);
        }
        s += __shfl_xor(s, 1); s += __shfl_xor(s, 2);
        s += __shfl_xor(s, 4); s += __shfl_xor(s, 8);
        if (l15 == 0) { sMw[ww] = m; sSw[ww] = s; }
    }
    __syncthreads();

    // ---- merged softmax scales -> LDS (visible after PV1 barrier)
    if (t < 128) {
        const float mh = sMh[t], mw = sMw[t];
        const float M = fmaxf(mh, mw);
        const float S = sSh[t]*__expf(mh - M) + sSw[t]*__expf(mw - M);
        sScw[t] = __expf(mw - M) / S;
        sSch[t] = __expf(mh - M) / S;
    }
    // ---- prefetch O2 half1 (coalesced 2B; hides under PV1 MFMA)
    const u16* o2p = O2 + (size_t)(b*H_ + h)*W_*C_;
    u16 o2a[6][4];
    #pragma unroll
    for (int ct = 0; ct < 6; ++ct)
        #pragma unroll
        for (int r = 0; r < 4; ++r)
            o2a[ct][r] = o2p[(size_t)(wbase + r)*C_ + ct*16 + l15];

    // ---- PV half1 (non-swapped): D row=w=wbase+r, col=c=ct*16+l15
    f32x4 accO[6];
    #pragma unroll
    for (int i = 0; i < 6; ++i) accO[i] = (f32x4){0.f,0.f,0.f,0.f};
    #pragma unroll
    for (int ks = 0; ks < 4; ++ks) {
        const int ch = ks*4 + q;
        s16x8 afp = *(const s16x8*)(ldsP + arow*256 + ((ch ^ (arow & 7)) << 4));
        #pragma unroll
        for (int ct = 0; ct < 6; ++ct) {
            const int vr = (ct << 4) + l15;
            s16x8 bfv = *(const s16x8*)(ldsV + vr*256 + ((ch ^ (vr & 7)) << 4));
            accO[ct] = MFMA_BF16(afp, bfv, accO[ct], 0, 0, 0);
        }
    }
    __syncthreads();                         // PV1 done reading ldsV; scales visible

    // ---- ds_write V half2 ((lc+96)&7 == lc&7)
    #pragma unroll
    for (int i = 0; i < 3; ++i) {
        const int idx = i*512 + t;
        const int lc = idx >> 4, o = idx & 15;
        *(s16x8*)(ldsV + lc*256 + ((o ^ (lc & 7)) << 4)) = vh2[i];
    }
    // ---- prefetch O2 half2 (hides under epilogue1 stores + PV2)
    u16 o2b[6][4];
    #pragma unroll
    for (int ct = 0; ct < 6; ++ct)
        #pragma unroll
        for (int r = 0; r < 4; ++r)
            o2b[ct][r] = o2p[(size_t)(wbase + r)*C_ + 96 + ct*16 + l15];

    // ---- per-thread scales for its 4 w's
    float scw[4], sch[4];
    #pragma unroll
    for (int r = 0; r < 4; ++r) { scw[r] = sScw[wbase + r]; sch[r] = sSch[wbase + r]; }

    // ---- epilogue half1: f32x4 stores, c 0..95
    #pragma unroll
    for (int ct = 0; ct < 6; ++ct) {
        f32x4 res;
        #pragma unroll
        for (int r = 0; r < 4; ++r)
            res[r] = gam*(accO[ct][r]*scw[r] + b2f(o2a[ct][r])*sch[r]) + xp1[ct][r];
        *(f32x4*)(void*)(out + (size_t)(b*C_ + ct*16 + l15)*HW_ + h*W_ + wbase) = res;
    }
    __syncthreads();                         // V half2 visible

    // ---- prefetch x half2 (hides under PV2 MFMA)
    f32x4 xp2[6];
    #pragma unroll
    for (int ct = 0; ct < 6; ++ct)
        xp2[ct] = *(const f32x4*)(const void*)
                  (x + (size_t)(b*C_ + 96 + ct*16 + l15)*HW_ + h*W_ + wbase);

    // ---- PV half2: c 96..191
    f32x4 accO2[6];
    #pragma unroll
    for (int i = 0; i < 6; ++i) accO2[i] = (f32x4){0.f,0.f,0.f,0.f};
    #pragma unroll
    for (int ks = 0; ks < 4; ++ks) {
        const int ch = ks*4 + q;
        s16x8 afp = *(const s16x8*)(ldsP + arow*256 + ((ch ^ (arow & 7)) << 4));
        #pragma unroll
        for (int ct = 0; ct < 6; ++ct) {
            const int lr = (ct << 4) + l15;
            s16x8 bfv = *(const s16x8*)(ldsV + lr*256 + ((ch ^ (lr & 7)) << 4));
            accO2[ct] = MFMA_BF16(afp, bfv, accO2[ct], 0, 0, 0);
        }
    }
    // ---- epilogue half2: c 96..191
    #pragma unroll
    for (int ct = 0; ct < 6; ++ct) {
        f32x4 res;
        #pragma unroll
        for (int r = 0; r < 4; ++r)
            res[r] = gam*(accO2[ct][r]*scw[r] + b2f(o2b[ct][r])*sch[r]) + xp2[ct][r];
        *(f32x4*)(void*)(out + (size_t)(b*C_ + 96 + ct*16 + l15)*HW_ + h*W_ + wbase) = res;
    }
}

extern "C" void kernel_launch(void* const* d_in, const int* in_sizes, int n_in,
                              void* d_out, int out_size, void* d_ws, size_t ws_size,
                              hipStream_t stream)
{
    const float* x  = (const float*)d_in[0];
    const float* Wq = (const float*)d_in[1];
    const float* bq = (const float*)d_in[2];
    const float* Wk = (const float*)d_in[3];
    const float* bk = (const float*)d_in[4];
    const float* Wv = (const float*)d_in[5];
    const float* bv = (const float*)d_in[6];
    const float* gm = (const float*)d_in[7];
    float* out = (float*)d_out;

    u16* Qc = (u16*)d_ws;
    u16* Kc = Qc + 8388608;
    u16* Vn = Kc + 8388608;
    u16* Vc = Vn + 25165824;
    u16* O2 = Vc + 25165824;                 // 25165824 u16
    u16* xT = O2;                            // alias: xT dead before kC writes O2
    float* Mh = (float*)(O2 + 25165824);
    float* Sh = Mh + 131072;
    u16*  Wb = (u16*)(Sh + 131072);          // 61440 u16
    float* Bb = (float*)(Wb + 61440);        // 320 f32

    hipLaunchKernelGGL(kwcast, dim3(320), dim3(256), 0, stream,
                       Wq, bq, Wk, bk, Wv, bv, Wb, Bb);
    hipLaunchKernelGGL(kxt, dim3(H_, B_), dim3(256), 0, stream, x, xT);
    hipLaunchKernelGGL(kprojM, dim3(H_, B_), dim3(256), 0, stream,
                       xT, Wb, Bb, Qc, Kc, Vn);
    hipLaunchKernelGGL(ktrv, dim3(C_, B_), dim3(256), 0, stream, Vn, Vc);
    hipLaunchKernelGGL(kC, dim3(W_, B_), dim3(512), 81920, stream,
                       Qc, Kc, Vc, O2, Mh, Sh);
    hipLaunchKernelGGL(kR, dim3(H_, B_), dim3(512), 60416, stream,
                       Qc, Kc, Vn, O2, Mh, Sh, x, gm, out);
}